// Round 1
// baseline (201.069 us; speedup 1.0000x reference)
//
#include <hip/hip_runtime.h>

// LinearCRF: mean_b( logZ_b - gold_b ), B=8192, L=1024, S=3.
// Scaled linear-domain forward: lane owns a 16-step chunk, builds the 3x3
// transfer-matrix product in linear space with exact power-of-2 renorm;
// 6-stage ordered shfl_xor butterfly composes 64 chunks per wave
// (1 wave = 1 sequence). Gold score fused.
// R4: coalesced loads + LDS redistribution. R3's per-lane AoS loads
// (192B/64B lane stride) cost 4x L1/L2 transactions per instruction and
// re-serialized into latency round-trips (VALUBusy 27%, HBM 16%).
// Now each wave loads its 20.5KB contiguously (lane i <- base + i*16B),
// scatters into a 5.9KB/wave LDS buffer in 4 software-pipelined passes,
// and 16 consumer lanes per pass read their chunk rows back (padded rows:
// em [16][13]f4, mk/tg [16][5] -> <=2-way bank conflict = free).
// Also: 9-entry trans-score LDS LUT replaces the per-step cndmask chain,
// tags packed 2b each into one VGPR. launch_bounds(256,4) caps VGPR at 128.

#define LOG2E 1.4426950408889634f
#define LN2   0.6931471805599453f

constexpr int B = 8192;
constexpr int L = 1024;
constexpr int SEQS_PER_BLOCK = 4;   // 4 waves of 64 per block

__device__ __forceinline__ float fexp2(float x) { return __builtin_amdgcn_exp2f(x); }
__device__ __forceinline__ float flog2(float x) { return __builtin_amdgcn_logf(x); }

__device__ __forceinline__ float f4get(const float4& v, int c) {
  return c == 0 ? v.x : (c == 1 ? v.y : (c == 2 ? v.z : v.w));
}

__device__ __forceinline__ float mux3(float x0, float x1, float x2, int i) {
  return (i == 0) ? x0 : ((i == 1) ? x1 : x2);
}

__device__ __forceinline__ void matmul3(float* __restrict__ D,
                                        const float* __restrict__ A,
                                        const float* __restrict__ Bm) {
  #pragma unroll
  for (int i = 0; i < 3; ++i)
    #pragma unroll
    for (int j = 0; j < 3; ++j)
      D[i * 3 + j] = A[i * 3 + 0] * Bm[0 * 3 + j] +
                     A[i * 3 + 1] * Bm[1 * 3 + j] +
                     A[i * 3 + 2] * Bm[2 * 3 + j];
}

// Exact power-of-2 renormalization: P *= 2^-ex, scale += ex.
__device__ __forceinline__ void renorm3(float* __restrict__ P, float& scale) {
  float m = P[0];
  #pragma unroll
  for (int e = 1; e < 9; ++e) m = fmaxf(m, P[e]);
  int ex;
  (void)frexpf(m, &ex);
  #pragma unroll
  for (int e = 0; e < 9; ++e) P[e] = ldexpf(P[e], -ex);
  scale += (float)ex;
}

__global__ __launch_bounds__(256, 4) void crf_main(
    const float* __restrict__ em, const float* __restrict__ mask,
    const float* __restrict__ trans, const int* __restrict__ tags,
    float* __restrict__ out) {
  const int lane = threadIdx.x & 63;
  const int wid = threadIdx.x >> 6;
  const int b = blockIdx.x * SEQS_PER_BLOCK + wid;

  // Per-wave staging buffers (padded rows -> conflict-free reads) + LUT.
  __shared__ float4 sEm[SEQS_PER_BLOCK][16][13];  // 13.0 KB
  __shared__ float4 sMk[SEQS_PER_BLOCK][16][5];   //  5.0 KB
  __shared__ int4   sTg[SEQS_PER_BLOCK][16][5];   //  5.0 KB
  __shared__ float  sT2[12];                      // 9 used: trans * log2(e)
  __shared__ float  red[SEQS_PER_BLOCK];

  if (threadIdx.x < 9) sT2[threadIdx.x] = trans[threadIdx.x] * LOG2E;
  __syncthreads();

  const float4* emG = (const float4*)em + (size_t)b * 768;
  const float4* mkG = (const float4*)mask + (size_t)b * 256;
  const int4*   tgG = (const int4*)tags + (size_t)b * 256;

  // em scatter slots: c-th coalesced load lands at m = 64c+lane
  // -> consumer row m/12, col m%12 (row-padded to 13 float4).
  int wrow[3], wcol[3];
  #pragma unroll
  for (int c = 0; c < 3; ++c) {
    const int m = 64 * c + lane;
    wrow[c] = m / 12;
    wcol[c] = m - 12 * wrow[c];
  }
  const int grp = lane >> 4;    // which pass serves this lane's chunk
  const int cl = lane & 15;     // consumer row within the pass
  const int mrow = lane >> 2, mcol = lane & 3;

  float4 E[12];
  float4 MKv[4];
  unsigned tpack = 0;           // 16 tags x 2 bits

  // ---- 4 software-pipelined staging passes (coalesced loads) ----
  float4 e0 = emG[lane], e1 = emG[64 + lane], e2 = emG[128 + lane];
  float4 mk = mkG[lane];
  int4   tg = tgG[lane];
  #pragma unroll
  for (int p = 0; p < 4; ++p) {
    float4 f0, f1, f2, fm;
    int4 ft;
    if (p < 3) {  // issue next pass's global loads first: latency overlap
      f0 = emG[192 * (p + 1) + lane];
      f1 = emG[192 * (p + 1) + 64 + lane];
      f2 = emG[192 * (p + 1) + 128 + lane];
      fm = mkG[64 * (p + 1) + lane];
      ft = tgG[64 * (p + 1) + lane];
    }
    // WAR: previous pass's ds_reads must complete before overwrite.
    if (p) asm volatile("s_waitcnt lgkmcnt(0)" ::: "memory");
    sEm[wid][wrow[0]][wcol[0]] = e0;
    sEm[wid][wrow[1]][wcol[1]] = e1;
    sEm[wid][wrow[2]][wcol[2]] = e2;
    sMk[wid][mrow][mcol] = mk;
    sTg[wid][mrow][mcol] = tg;
    // RAW: this pass's ds_writes visible before consumer reads.
    asm volatile("s_waitcnt lgkmcnt(0)" ::: "memory");
    if (grp == p) {
      #pragma unroll
      for (int u = 0; u < 12; ++u) E[u] = sEm[wid][cl][u];
      #pragma unroll
      for (int u = 0; u < 4; ++u) MKv[u] = sMk[wid][cl][u];
      #pragma unroll
      for (int u = 0; u < 4; ++u) {
        const int4 t = sTg[wid][cl][u];
        tpack |= (unsigned)(t.x | (t.y << 2) | (t.z << 4) | (t.w << 6)) << (8 * u);
      }
    }
    if (p < 3) { e0 = f0; e1 = f1; e2 = f2; mk = fm; tg = ft; }
  }

  // Transitions in linear form for the matrix step (uniform -> s_load + exp2).
  float tk[9];
  #pragma unroll
  for (int e = 0; e < 9; ++e) tk[e] = fexp2(trans[e] * LOG2E);

  float P[9] = {1.f, 0.f, 0.f, 0.f, 1.f, 0.f, 0.f, 0.f, 1.f};
  float scale = 0.f, gold = 0.f;
  float a0 = 0.f, a1 = 0.f, a2 = 0.f;   // step-0 linear emissions (lane 0)
  float e0_sel = 0.f, mk0 = 0.f;        // deferred step-0 gold term
  const int tag0 = tpack & 3;
  int prev = 0;

  #pragma unroll
  for (int s = 0; s < 16; ++s) {
    const float ev0 = f4get(E[(3 * s + 0) >> 2], (3 * s + 0) & 3) * LOG2E;
    const float ev1 = f4get(E[(3 * s + 1) >> 2], (3 * s + 1) & 3) * LOG2E;
    const float ev2 = f4get(E[(3 * s + 2) >> 2], (3 * s + 2) & 3) * LOG2E;
    const float m   = f4get(MKv[s >> 2], s & 3);
    const int   cur = (tpack >> (2 * s)) & 3;

    // ---- gold score (log2 domain); trans score via LDS LUT ----
    const float e = mux3(ev0, ev1, ev2, cur);
    if (s == 0) {
      e0_sel = e; mk0 = m;               // cross-lane prev tag fixed up later
    } else {
      gold = fmaf(sT2[3 * prev + cur] + e, m, gold);
    }
    prev = cur;

    // ---- matrix step (linear domain): M = act ? tk.*w : I ----
    const float w0 = fexp2(ev0);
    const float w1 = fexp2(ev1);
    const float w2 = fexp2(ev2);
    if (s == 0) { a0 = w0; a1 = w1; a2 = w2; }
    const bool act = (m > 0.f) && !(s == 0 && lane == 0);  // t=0 is alpha0
    const float g  = act ? 1.f : 0.f;
    const float c1 = 1.f - g;
    const float u0 = w0 * g, u1 = w1 * g, u2 = w2 * g;
    float M[9];
    M[0] = fmaf(tk[0], u0, c1); M[1] = tk[1] * u1;           M[2] = tk[2] * u2;
    M[3] = tk[3] * u0;          M[4] = fmaf(tk[4], u1, c1);  M[5] = tk[5] * u2;
    M[6] = tk[6] * u0;          M[7] = tk[7] * u1;           M[8] = fmaf(tk[8], u2, c1);
    float N[9];
    matmul3(N, P, M);
    #pragma unroll
    for (int e2 = 0; e2 < 9; ++e2) P[e2] = N[e2];

    if (s == 7 || s == 15) renorm3(P, scale);  // bound fp32 range
  }

  // ---- deferred step-0 gold term (needs previous lane's last tag) ----
  const int prevLast = __shfl_up(prev, 1);     // prev == tag15 here
  const float t0 = sT2[3 * prevLast + tag0];
  gold = fmaf((lane == 0 ? 0.f : t0) + e0_sel, mk0, gold);
  #pragma unroll
  for (int d = 1; d < 64; d <<= 1) gold += __shfl_xor(gold, d, 64);

  // ---- ordered butterfly combine (entries <= 3^6 = 729: no renorm needed) ----
  #pragma unroll
  for (int d = 1; d < 64; d <<= 1) {
    float o[9];
    #pragma unroll
    for (int e = 0; e < 9; ++e) o[e] = __shfl_xor(P[e], d, 64);
    const float osc = __shfl_xor(scale, d, 64);
    const bool later = (lane & d) != 0;  // self covers the later time segment
    float A[9], Bm[9];
    #pragma unroll
    for (int e = 0; e < 9; ++e) {
      A[e]  = later ? o[e] : P[e];
      Bm[e] = later ? P[e] : o[e];
    }
    float N[9];
    matmul3(N, A, Bm);
    #pragma unroll
    for (int e = 0; e < 9; ++e) P[e] = N[e];
    scale += osc;
  }

  // ---- finalize + block reduce + atomic ----
  if (lane == 0) {
    const float z = a0 * (P[0] + P[1] + P[2]) +
                    a1 * (P[3] + P[4] + P[5]) +
                    a2 * (P[6] + P[7] + P[8]);
    red[wid] = LN2 * (scale + flog2(z) - gold);
  }
  __syncthreads();
  if (threadIdx.x == 0) {
    const float s = red[0] + red[1] + red[2] + red[3];
    atomicAdd(out, s * (1.0f / (float)B));
  }
}

extern "C" void kernel_launch(void* const* d_in, const int* in_sizes, int n_in,
                              void* d_out, int out_size, void* d_ws, size_t ws_size,
                              hipStream_t stream) {
  const float* em    = (const float*)d_in[0];
  const float* mask  = (const float*)d_in[1];
  const float* trans = (const float*)d_in[2];
  const int*   tags  = (const int*)d_in[3];
  float* out = (float*)d_out;

  hipMemsetAsync(out, 0, sizeof(float), stream);  // atomic accumulator init
  crf_main<<<B / SEQS_PER_BLOCK, 256, 0, stream>>>(em, mask, trans, tags, out);
}